// Round 6
// baseline (203.205 us; speedup 1.0000x reference)
//
#include <hip/hip_runtime.h>

#define NSEQ 2048
#define DIM  512
#define KVBLK 32
#define NKT  64                    // 2048 / 32
#define TILEB 32768                // 32*512*2 bytes (bf16 tile)
#define SMEMB (4 * TILEB + 8192)   // K0,K1,V0,V1 + 8KB per-wave P-lds

typedef __bf16 bf16x8 __attribute__((ext_vector_type(8)));
typedef float  f32x4  __attribute__((ext_vector_type(4)));

__device__ __forceinline__ void gld16(const void* g, void* l) {
  __builtin_amdgcn_global_load_lds(
      (const __attribute__((address_space(1))) unsigned int*)g,
      (__attribute__((address_space(3))) unsigned int*)l, 16, 0, 0);
}

// ---------- pre-pass: K -> bf16, per-tile [32 kv][512 d], byte ^= ((row&7)<<4)
__global__ __launch_bounds__(256) void prep_k(const float* __restrict__ ks,
                                              char* __restrict__ kp) {
  int b = blockIdx.x >> 6, kt = blockIdx.x & 63;
  int t = threadIdx.x;
  const float* src = ks + ((size_t)(b * NSEQ + kt * KVBLK)) * DIM;
  char* dst = kp + ((size_t)(b * 64 + kt)) * TILEB;
#pragma unroll
  for (int i = 0; i < 8; ++i) {
    int c = t + i * 256;
    int row = c >> 6;
    int d0 = (c & 63) * 8;
    const float4* s4 = (const float4*)(src + row * DIM + d0);
    float4 x = s4[0], y = s4[1];
    bf16x8 h;
    h[0] = (__bf16)x.x; h[1] = (__bf16)x.y; h[2] = (__bf16)x.z; h[3] = (__bf16)x.w;
    h[4] = (__bf16)y.x; h[5] = (__bf16)y.y; h[6] = (__bf16)y.z; h[7] = (__bf16)y.w;
    *(bf16x8*)(dst + row * 1024 + ((d0 * 2) ^ ((row & 7) << 4))) = h;
  }
}

// ---------- pre-pass: V -> bf16 transposed per tile (verified layout):
// byte(d,kv) = (d>>1)*128 + ((((d&1)*64) + kv*2) ^ (((d>>1)&7)<<4))
__global__ __launch_bounds__(256) void prep_v(const float* __restrict__ vs,
                                              char* __restrict__ vtp) {
  __shared__ __align__(16) char lds[TILEB];
  int b = blockIdx.x >> 6, kt = blockIdx.x & 63;
  int t = threadIdx.x;
  const float* src = vs + ((size_t)(b * NSEQ + kt * KVBLK)) * DIM;
#pragma unroll
  for (int i = 0; i < 8; ++i) {
    int c = t + i * 256;
    int kv = c >> 6;
    int d0 = (c & 63) * 8;
    const float4* s4 = (const float4*)(src + kv * DIM + d0);
    float4 x = s4[0], y = s4[1];
    float vals[8] = {x.x, x.y, x.z, x.w, y.x, y.y, y.z, y.w};
#pragma unroll
    for (int j = 0; j < 8; ++j) {
      int d = d0 + j;
      int byte = (d >> 1) * 128 + (((((d & 1) * 64) + kv * 2)) ^ (((d >> 1) & 7) << 4));
      *(__bf16*)(lds + byte) = (__bf16)vals[j];
    }
  }
  __syncthreads();
  char* dst = vtp + ((size_t)(b * 64 + kt)) * TILEB;
#pragma unroll
  for (int i = 0; i < 8; ++i) {
    int c16 = t + i * 256;
    *(bf16x8*)(dst + c16 * 16) = *(const bf16x8*)(lds + c16 * 16);
  }
}

// ---------- main: 8 independent waves x 16q = 128 q/block (4x staging reuse),
// 2 waves/SIMD, per-wave 2-stage pipeline QK(t+1) || PV(t)
__global__ __launch_bounds__(512, 2) void attn_main(
    const float* __restrict__ qs, const char* __restrict__ kp,
    const char* __restrict__ vtp, const float* __restrict__ scale,
    float* __restrict__ out) {
  extern __shared__ __align__(16) char smem[];
  int b  = blockIdx.x & 7;          // batch -> XCD (L2 locality)
  int qt = blockIdx.x >> 3;         // 0..15
  int tid = threadIdx.x;
  int w = tid >> 6, lane = tid & 63;
  int c = lane & 15, g = lane >> 4;
  int q0 = qt * 128 + w * 16;

  char* kbuf = smem;                // kbuf + (i&1)*TILEB
  char* vbuf = smem + 2 * TILEB;    // vbuf + (i&1)*TILEB
  char* plds = smem + 4 * TILEB + w * 1024;

  float cc = 1.4426950408889634f / scale[0];   // log2(e)/scale folded into Q

  // Q fragments (B-operand for swapped QK; lane holds Q[q=c][k*32+g*8..+7])
  bf16x8 qf[16];
#pragma unroll
  for (int k = 0; k < 16; ++k) {
    int d = k * 32 + g * 8;
    const float4* p = (const float4*)(qs + ((size_t)(b * NSEQ + q0 + c)) * DIM + d);
    float4 x = p[0], y = p[1];
    float vals[8] = {x.x, x.y, x.z, x.w, y.x, y.y, y.z, y.w};
    bf16x8 h;
#pragma unroll
    for (int j = 0; j < 8; ++j) {
      float mlt = (d + j == 0) ? cc : -cc;     // Minkowski sign fold
      h[j] = (__bf16)(vals[j] * mlt);
    }
    qf[k] = h;
  }

  f32x4 acc[32];
#pragma unroll
  for (int i = 0; i < 32; ++i) acc[i] = (f32x4){0.f, 0.f, 0.f, 0.f};
  float mrow = -1e30f;               // running max for q=c (lane-local)

  const char* kpb = kp  + (size_t)b * 64 * TILEB;
  const char* vpb = vtp + (size_t)b * 64 * TILEB;

  const int csw = (c & 7) << 4;                // K swizzle term
  const int vt_lane = (c >> 1) * 128 +
      (((((c & 1) * 64) + g * 16)) ^ (((c >> 1) & 7) << 4));  // V/P A-frag read
  const int qb = (c >> 1) * 128;               // P write-side (q=c per lane)
  const int qh = (c & 1) * 64;
  const int qx = ((c >> 1) & 7) << 4;

  // prologue: stage K(0), V(0), K(1)  (512 threads x 16B x 4 = 32KB per tile)
#pragma unroll
  for (int i = 0; i < 4; ++i) {
    int o = tid * 16 + i * 8192;
    gld16(kpb + o, kbuf + o);
    gld16(vpb + o, vbuf + o);
    gld16(kpb + TILEB + o, kbuf + TILEB + o);
  }
  __syncthreads();

  f32x4 sl, sh;
  bf16x8 pf;

  // ---- QK(0) + softmax(0) + P(0)
  {
    f32x4 sa0 = {0.f,0.f,0.f,0.f}, sb0 = {0.f,0.f,0.f,0.f};
    f32x4 sa1 = {0.f,0.f,0.f,0.f}, sb1 = {0.f,0.f,0.f,0.f};
    const char* krl = kbuf + c * 1024;
    const char* krh = krl + 16 * 1024;
#pragma unroll
    for (int k = 0; k < 16; ++k) {
      int bir = (k * 64 + g * 16) ^ csw;
      bf16x8 kfl = *(const bf16x8*)(krl + bir);
      bf16x8 kfh = *(const bf16x8*)(krh + bir);
      if (k & 1) {
        sb0 = __builtin_amdgcn_mfma_f32_16x16x32_bf16(kfl, qf[k], sb0, 0, 0, 0);
        sb1 = __builtin_amdgcn_mfma_f32_16x16x32_bf16(kfh, qf[k], sb1, 0, 0, 0);
      } else {
        sa0 = __builtin_amdgcn_mfma_f32_16x16x32_bf16(kfl, qf[k], sa0, 0, 0, 0);
        sa1 = __builtin_amdgcn_mfma_f32_16x16x32_bf16(kfh, qf[k], sa1, 0, 0, 0);
      }
    }
    sl = sa0 + sb0; sh = sa1 + sb1;
    float mm = fmaxf(fmaxf(fmaxf(sl[0], sl[1]), fmaxf(sl[2], sl[3])),
                     fmaxf(fmaxf(sh[0], sh[1]), fmaxf(sh[2], sh[3])));
    mm = fmaxf(mm, __shfl_xor(mm, 16));
    mm = fmaxf(mm, __shfl_xor(mm, 32));
    mrow = mm;                                  // first tile: just set
#pragma unroll
    for (int r = 0; r < 4; ++r) {
      float pvl = exp2f(sl[r] - mrow);
      float pvh = exp2f(sh[r] - mrow);
      int kvl = 4 * g + r;
      *(__bf16*)(plds + qb + ((qh + kvl * 2) ^ qx))        = (__bf16)pvl;
      *(__bf16*)(plds + qb + ((qh + (16 + kvl) * 2) ^ qx)) = (__bf16)pvh;
    }
    pf = *(const bf16x8*)(plds + vt_lane);
  }
  __syncthreads();   // protect kbuf0 (all waves done with QK(0)) before K(2) stage

  // ---- pipelined main loop: iter t does QK(t+1) || PV(t)
  for (int t = 0; t < NKT - 1; ++t) {
    // stage K(t+2) -> kbuf[t&1], V(t+1) -> vbuf[(t+1)&1]  (targets idle since t-1)
    if (t + 2 < NKT) {
      const char* ksrc = kpb + (size_t)(t + 2) * TILEB;
      char* kdst = kbuf + (t & 1) * TILEB;
#pragma unroll
      for (int i = 0; i < 4; ++i) {
        int o = tid * 16 + i * 8192;
        gld16(ksrc + o, kdst + o);
      }
    }
    {
      const char* vsrc = vpb + (size_t)(t + 1) * TILEB;
      char* vdst = vbuf + ((t + 1) & 1) * TILEB;
#pragma unroll
      for (int i = 0; i < 4; ++i) {
        int o = tid * 16 + i * 8192;
        gld16(vsrc + o, vdst + o);
      }
    }

    // ---- merged region: QK(t+1) reads kbuf[(t+1)&1]; PV(t) reads vbuf[t&1]
    f32x4 sa0 = {0.f,0.f,0.f,0.f}, sb0 = {0.f,0.f,0.f,0.f};
    f32x4 sa1 = {0.f,0.f,0.f,0.f}, sb1 = {0.f,0.f,0.f,0.f};
    const char* krl = kbuf + ((t + 1) & 1) * TILEB + c * 1024;
    const char* krh = krl + 16 * 1024;
    const char* vr  = vbuf + (t & 1) * TILEB + vt_lane;
#pragma unroll
    for (int k = 0; k < 16; ++k) {
      int bir = (k * 64 + g * 16) ^ csw;
      bf16x8 kfl = *(const bf16x8*)(krl + bir);
      bf16x8 kfh = *(const bf16x8*)(krh + bir);
      bf16x8 vf0 = *(const bf16x8*)(vr + (2 * k) * 1024);
      bf16x8 vf1 = *(const bf16x8*)(vr + (2 * k + 1) * 1024);
      if (k & 1) {
        sb0 = __builtin_amdgcn_mfma_f32_16x16x32_bf16(kfl, qf[k], sb0, 0, 0, 0);
        sb1 = __builtin_amdgcn_mfma_f32_16x16x32_bf16(kfh, qf[k], sb1, 0, 0, 0);
      } else {
        sa0 = __builtin_amdgcn_mfma_f32_16x16x32_bf16(kfl, qf[k], sa0, 0, 0, 0);
        sa1 = __builtin_amdgcn_mfma_f32_16x16x32_bf16(kfh, qf[k], sa1, 0, 0, 0);
      }
      acc[2 * k]     = __builtin_amdgcn_mfma_f32_16x16x32_bf16(pf, vf0, acc[2 * k], 0, 0, 0);
      acc[2 * k + 1] = __builtin_amdgcn_mfma_f32_16x16x32_bf16(pf, vf1, acc[2 * k + 1], 0, 0, 0);
    }
    sl = sa0 + sb0; sh = sa1 + sb1;

    // ---- softmax(t+1) (lane-local row q=c; reduce over g only)
    float mm = fmaxf(fmaxf(fmaxf(sl[0], sl[1]), fmaxf(sl[2], sl[3])),
                     fmaxf(fmaxf(sh[0], sh[1]), fmaxf(sh[2], sh[3])));
    mm = fmaxf(mm, __shfl_xor(mm, 16));
    mm = fmaxf(mm, __shfl_xor(mm, 32));
    if (__any(mm > mrow + 11.0f)) {          // defer-max (2^11 headroom)
      float mn = fmaxf(mrow, mm);
      float f = exp2f(mrow - mn);
      mrow = mn;
      float f0 = __shfl(f, 4 * g + 0), f1 = __shfl(f, 4 * g + 1);
      float f2 = __shfl(f, 4 * g + 2), f3 = __shfl(f, 4 * g + 3);
#pragma unroll
      for (int i = 0; i < 32; ++i) {
        acc[i][0] *= f0; acc[i][1] *= f1; acc[i][2] *= f2; acc[i][3] *= f3;
      }
    }

    // ---- P(t+1) write + A-frag read (per-wave LDS, no barrier needed)
#pragma unroll
    for (int r = 0; r < 4; ++r) {
      float pvl = exp2f(sl[r] - mrow);
      float pvh = exp2f(sh[r] - mrow);
      int kvl = 4 * g + r;
      *(__bf16*)(plds + qb + ((qh + kvl * 2) ^ qx))        = (__bf16)pvl;
      *(__bf16*)(plds + qb + ((qh + (16 + kvl) * 2) ^ qx)) = (__bf16)pvh;
    }
    pf = *(const bf16x8*)(plds + vt_lane);

    __syncthreads();   // drain stages; all waves done reading this iter's buffers
  }

  // ---- tail: PV(NKT-1)
  {
    const char* vr = vbuf + ((NKT - 1) & 1) * TILEB + vt_lane;
#pragma unroll
    for (int dtl = 0; dtl < 32; ++dtl) {
      bf16x8 vf = *(const bf16x8*)(vr + dtl * 1024);
      acc[dtl] = __builtin_amdgcn_mfma_f32_16x16x32_bf16(pf, vf, acc[dtl], 0, 0, 0);
    }
  }

  // ---- epilogue: Lorentz normalization (softmax denom cancels; EPS preserved)
#pragma unroll
  for (int r = 0; r < 4; ++r) {
    float ss = 0.f;
#pragma unroll
    for (int dtl = 0; dtl < 32; ++dtl) ss += acc[dtl][r] * acc[dtl][r];
    ss += __shfl_xor(ss, 1);
    ss += __shfl_xor(ss, 2);
    ss += __shfl_xor(ss, 4);
    ss += __shfl_xor(ss, 8);
    float a0 = __shfl(acc[0][r], lane & 48);   // lane c==0 holds O[q][0]
    float d2 = fabsf(2.f * a0 * a0 - ss);
    float inv = rsqrtf(fmaxf(d2, 1e-8f));
    float* orow = out + ((size_t)(b * NSEQ + q0 + 4 * g + r)) * DIM + c;
#pragma unroll
    for (int dtl = 0; dtl < 32; ++dtl) orow[dtl * 16] = acc[dtl][r] * inv;
  }
}

extern "C" void kernel_launch(void* const* d_in, const int* in_sizes, int n_in,
                              void* d_out, int out_size, void* d_ws, size_t ws_size,
                              hipStream_t stream) {
  (void)in_sizes; (void)n_in; (void)out_size;
  const float* qs = (const float*)d_in[0];
  const float* ks = (const float*)d_in[1];
  const float* vs = (const float*)d_in[2];
  const float* scale = (const float*)d_in[3];
  // d_in[4] (bias) is uniform across softmax axis -> invariant -> unused
  float* out = (float*)d_out;

  size_t need = (size_t)2 * 8 * 64 * TILEB;   // 33.5 MB
  if (ws_size < need) return;
  char* kp  = (char*)d_ws;
  char* vtp = (char*)d_ws + (size_t)8 * 64 * TILEB;

  hipFuncSetAttribute((const void*)attn_main,
                      hipFuncAttributeMaxDynamicSharedMemorySize, SMEMB);

  prep_k<<<512, 256, 0, stream>>>(ks, kp);
  prep_v<<<512, 256, 0, stream>>>(vs, vtp);
  attn_main<<<128, 512, SMEMB, stream>>>(qs, kp, vtp, scale, out);
}

// Round 7
// 179.528 us; speedup vs baseline: 1.1319x; 1.1319x over previous
//
#include <hip/hip_runtime.h>

#define NSEQ 2048
#define DIM  512
#define KVBLK 32
#define NKT  64                    // 2048 / 32
#define TILEB 32768                // 32*512*2 bytes (bf16 tile)
#define SMEMB (4 * TILEB + 8192)   // K0,K1,V0,V1 + 8x1KB per-wave P-lds

typedef __bf16 bf16x8 __attribute__((ext_vector_type(8)));
typedef float  f32x4  __attribute__((ext_vector_type(4)));

__device__ __forceinline__ void gld16(const void* g, void* l) {
  __builtin_amdgcn_global_load_lds(
      (const __attribute__((address_space(1))) unsigned int*)g,
      (__attribute__((address_space(3))) unsigned int*)l, 16, 0, 0);
}

// ---------- pre-pass: K -> bf16, per-tile [32 kv][512 d], byte ^= ((row&7)<<4)
__global__ __launch_bounds__(256) void prep_k(const float* __restrict__ ks,
                                              char* __restrict__ kp) {
  int b = blockIdx.x >> 6, kt = blockIdx.x & 63;
  int t = threadIdx.x;
  const float* src = ks + ((size_t)(b * NSEQ + kt * KVBLK)) * DIM;
  char* dst = kp + ((size_t)(b * 64 + kt)) * TILEB;
#pragma unroll
  for (int i = 0; i < 8; ++i) {
    int c = t + i * 256;
    int row = c >> 6;
    int d0 = (c & 63) * 8;
    const float4* s4 = (const float4*)(src + row * DIM + d0);
    float4 x = s4[0], y = s4[1];
    bf16x8 h;
    h[0] = (__bf16)x.x; h[1] = (__bf16)x.y; h[2] = (__bf16)x.z; h[3] = (__bf16)x.w;
    h[4] = (__bf16)y.x; h[5] = (__bf16)y.y; h[6] = (__bf16)y.z; h[7] = (__bf16)y.w;
    *(bf16x8*)(dst + row * 1024 + ((d0 * 2) ^ ((row & 7) << 4))) = h;
  }
}

// ---------- pre-pass: V -> bf16 transposed per tile (verified layout):
// byte(d,kv) = (d>>1)*128 + ((((d&1)*64) + kv*2) ^ (((d>>1)&7)<<4))
__global__ __launch_bounds__(256) void prep_v(const float* __restrict__ vs,
                                              char* __restrict__ vtp) {
  __shared__ __align__(16) char lds[TILEB];
  int b = blockIdx.x >> 6, kt = blockIdx.x & 63;
  int t = threadIdx.x;
  const float* src = vs + ((size_t)(b * NSEQ + kt * KVBLK)) * DIM;
#pragma unroll
  for (int i = 0; i < 8; ++i) {
    int c = t + i * 256;
    int kv = c >> 6;
    int d0 = (c & 63) * 8;
    const float4* s4 = (const float4*)(src + kv * DIM + d0);
    float4 x = s4[0], y = s4[1];
    float vals[8] = {x.x, x.y, x.z, x.w, y.x, y.y, y.z, y.w};
#pragma unroll
    for (int j = 0; j < 8; ++j) {
      int d = d0 + j;
      int byte = (d >> 1) * 128 + (((((d & 1) * 64) + kv * 2)) ^ (((d >> 1) & 7) << 4));
      *(__bf16*)(lds + byte) = (__bf16)vals[j];
    }
  }
  __syncthreads();
  char* dst = vtp + ((size_t)(b * 64 + kt)) * TILEB;
#pragma unroll
  for (int i = 0; i < 8; ++i) {
    int c16 = t + i * 256;
    *(bf16x8*)(dst + c16 * 16) = *(const bf16x8*)(lds + c16 * 16);
  }
}

// ---------- main: 8 waves = 4 pairs x 16q; parity p handles kv-half 16p..16p+15
// of every tile; independent R5-style pipelined chain per wave; end merge.
__global__ __launch_bounds__(512) void attn_main(
    const float* __restrict__ qs, const char* __restrict__ kp,
    const char* __restrict__ vtp, const float* __restrict__ scale,
    float* __restrict__ out) {
  extern __shared__ __align__(16) char smem[];
  int b  = blockIdx.x & 7;          // batch -> XCD (L2 locality)
  int qt = blockIdx.x >> 3;         // 0..31
  int tid = threadIdx.x;
  int w = tid >> 6, lane = tid & 63;
  int wq = w & 3, p = w >> 2;       // pair index, kv-parity
  int c = lane & 15, g = lane >> 4;
  int q0 = qt * 64 + wq * 16;
  const bool act = ((g >> 1) == p); // lanes whose A/B kv-half belongs to this wave

  char* kbuf = smem;                // + (i&1)*TILEB
  char* vbuf = smem + 2 * TILEB;    // + (i&1)*TILEB
  char* plds = smem + 4 * TILEB + w * 1024;

  float cc = 1.4426950408889634f / scale[0];   // log2(e)/scale folded into Q

  // Q fragments (B-operand for swapped QK; lane holds Q[q=c][k*32+g*8..+7])
  bf16x8 qf[16];
#pragma unroll
  for (int k = 0; k < 16; ++k) {
    int d = k * 32 + g * 8;
    const float4* ptr = (const float4*)(qs + ((size_t)(b * NSEQ + q0 + c)) * DIM + d);
    float4 x = ptr[0], y = ptr[1];
    float vals[8] = {x.x, x.y, x.z, x.w, y.x, y.y, y.z, y.w};
    bf16x8 h;
#pragma unroll
    for (int j = 0; j < 8; ++j) {
      float mlt = (d + j == 0) ? cc : -cc;     // Minkowski sign fold
      h[j] = (__bf16)(vals[j] * mlt);
    }
    qf[k] = h;
  }

  f32x4 acc[32];
#pragma unroll
  for (int i = 0; i < 32; ++i) acc[i] = (f32x4){0.f, 0.f, 0.f, 0.f};
  float mrow = -1e30f;               // running max for q=c over OWN kv-half

  const char* kpb = kp  + (size_t)b * 64 * TILEB;
  const char* vpb = vtp + (size_t)b * 64 * TILEB;

  const int csw = (c & 7) << 4;                // K swizzle term
  const int vt_lane = (c >> 1) * 128 +
      (((((c & 1) * 64) + g * 16)) ^ (((c >> 1) & 7) << 4));  // V/P A-frag read
  const int qb = (c >> 1) * 128;               // P write-side (q=c per lane)
  const int qh = (c & 1) * 64;
  const int qx = ((c >> 1) & 7) << 4;
  const bf16x8 zf = {};

  // prologue: stage K(0), V(0), K(1)  (512 threads x 16B x 4 = 32KB per tile)
#pragma unroll
  for (int i = 0; i < 4; ++i) {
    int o = tid * 16 + i * 8192;
    gld16(kpb + o, kbuf + o);
    gld16(vpb + o, vbuf + o);
    gld16(kpb + TILEB + o, kbuf + TILEB + o);
  }
  __syncthreads();

  f32x4 s;
  bf16x8 pf;

  // ---- QK(0) on own kv-half + P(0)
  {
    f32x4 sa = {0.f,0.f,0.f,0.f}, sb = {0.f,0.f,0.f,0.f};
    const char* kr = kbuf + (16 * p + c) * 1024;
#pragma unroll
    for (int k = 0; k < 16; ++k) {
      int bir = (k * 64 + g * 16) ^ csw;
      bf16x8 kf = *(const bf16x8*)(kr + bir);
      if (k & 1) sb = __builtin_amdgcn_mfma_f32_16x16x32_bf16(kf, qf[k], sb, 0, 0, 0);
      else       sa = __builtin_amdgcn_mfma_f32_16x16x32_bf16(kf, qf[k], sa, 0, 0, 0);
    }
    s = sa + sb;                              // reg r = S[q=c][kv=16p+4g+r]
    float mm = fmaxf(fmaxf(s[0], s[1]), fmaxf(s[2], s[3]));
    mm = fmaxf(mm, __shfl_xor(mm, 16));
    mm = fmaxf(mm, __shfl_xor(mm, 32));
    mrow = mm;
#pragma unroll
    for (int r = 0; r < 4; ++r) {
      float pv = exp2f(s[r] - mrow);
      int kvg = 16 * p + 4 * g + r;           // global kv slot in P
      *(__bf16*)(plds + qb + ((qh + kvg * 2) ^ qx)) = (__bf16)pv;
    }
    pf = act ? *(const bf16x8*)(plds + vt_lane) : zf;
  }
  __syncthreads();   // all waves done with kbuf0 before K(2) staging

  // ---- pipelined main loop: iter t does QK(t+1) || PV(t)
  for (int t = 0; t < NKT - 1; ++t) {
    if (t + 2 < NKT) {
      const char* ksrc = kpb + (size_t)(t + 2) * TILEB;
      char* kdst = kbuf + (t & 1) * TILEB;
#pragma unroll
      for (int i = 0; i < 4; ++i) {
        int o = tid * 16 + i * 8192;
        gld16(ksrc + o, kdst + o);
      }
    }
    {
      const char* vsrc = vpb + (size_t)(t + 1) * TILEB;
      char* vdst = vbuf + ((t + 1) & 1) * TILEB;
#pragma unroll
      for (int i = 0; i < 4; ++i) {
        int o = tid * 16 + i * 8192;
        gld16(vsrc + o, vdst + o);
      }
    }

    // ---- merged region: QK(t+1) on kbuf[(t+1)&1] kv-half || PV(t) on vbuf[t&1]
    f32x4 sa = {0.f,0.f,0.f,0.f}, sb = {0.f,0.f,0.f,0.f};
    const char* kr = kbuf + ((t + 1) & 1) * TILEB + (16 * p + c) * 1024;
    const char* vr = vbuf + (t & 1) * TILEB + vt_lane;
#pragma unroll
    for (int k = 0; k < 16; ++k) {
      int bir = (k * 64 + g * 16) ^ csw;
      bf16x8 kf = *(const bf16x8*)(kr + bir);
      bf16x8 vf0 = act ? *(const bf16x8*)(vr + (2 * k) * 1024)     : zf;
      bf16x8 vf1 = act ? *(const bf16x8*)(vr + (2 * k + 1) * 1024) : zf;
      if (k & 1) sb = __builtin_amdgcn_mfma_f32_16x16x32_bf16(kf, qf[k], sb, 0, 0, 0);
      else       sa = __builtin_amdgcn_mfma_f32_16x16x32_bf16(kf, qf[k], sa, 0, 0, 0);
      acc[2 * k]     = __builtin_amdgcn_mfma_f32_16x16x32_bf16(pf, vf0, acc[2 * k], 0, 0, 0);
      acc[2 * k + 1] = __builtin_amdgcn_mfma_f32_16x16x32_bf16(pf, vf1, acc[2 * k + 1], 0, 0, 0);
    }
    s = sa + sb;

    // ---- softmax(t+1) on own kv-half (lane-local q=c; reduce over g)
    float mm = fmaxf(fmaxf(s[0], s[1]), fmaxf(s[2], s[3]));
    mm = fmaxf(mm, __shfl_xor(mm, 16));
    mm = fmaxf(mm, __shfl_xor(mm, 32));
    if (__any(mm > mrow + 11.0f)) {          // defer-max (2^11 headroom)
      float mn = fmaxf(mrow, mm);
      float f = exp2f(mrow - mn);
      mrow = mn;
      float f0 = __shfl(f, 4 * g + 0), f1 = __shfl(f, 4 * g + 1);
      float f2 = __shfl(f, 4 * g + 2), f3 = __shfl(f, 4 * g + 3);
#pragma unroll
      for (int i = 0; i < 32; ++i) {
        acc[i][0] *= f0; acc[i][1] *= f1; acc[i][2] *= f2; acc[i][3] *= f3;
      }
    }

    // ---- P(t+1) write + A-frag read (per-wave LDS, no barrier needed)
#pragma unroll
    for (int r = 0; r < 4; ++r) {
      float pv = exp2f(s[r] - mrow);
      int kvg = 16 * p + 4 * g + r;
      *(__bf16*)(plds + qb + ((qh + kvg * 2) ^ qx)) = (__bf16)pv;
    }
    pf = act ? *(const bf16x8*)(plds + vt_lane) : zf;

    __syncthreads();   // drain stages; all waves done reading this iter's buffers
  }

  // ---- tail: PV(NKT-1)
  {
    const char* vr = vbuf + ((NKT - 1) & 1) * TILEB + vt_lane;
#pragma unroll
    for (int dtl = 0; dtl < 32; ++dtl) {
      bf16x8 vf = act ? *(const bf16x8*)(vr + dtl * 1024) : zf;
      acc[dtl] = __builtin_amdgcn_mfma_f32_16x16x32_bf16(pf, vf, acc[dtl], 0, 0, 0);
    }
  }

  // ---- pair merge: exchange m via plds, rescale both halves, add via LDS
  if (g == 0) *(float*)(plds + c * 4) = mrow;       // P area dead now
  __syncthreads();
  {
    float mpar = *(const float*)(smem + 4 * TILEB + (wq + 4 * (1 - p)) * 1024 + c * 4);
    float M = fmaxf(mrow, mpar);
    float f = exp2f(mrow - M);
    float f0 = __shfl(f, 4 * g + 0), f1 = __shfl(f, 4 * g + 1);
    float f2 = __shfl(f, 4 * g + 2), f3 = __shfl(f, 4 * g + 3);
#pragma unroll
    for (int i = 0; i < 32; ++i) {
      acc[i][0] *= f0; acc[i][1] *= f1; acc[i][2] *= f2; acc[i][3] *= f3;
    }
  }
  __syncthreads();                                   // K/V LDS area now reusable
  {
    char* mrg = smem + wq * 32768;                   // 32KB per pair
    if (p == 1) {
#pragma unroll
      for (int i = 0; i < 32; ++i)
        *(f32x4*)(mrg + i * 1024 + lane * 16) = acc[i];
    }
  }
  __syncthreads();
  if (p == 0) {
    char* mrg = smem + wq * 32768;
#pragma unroll
    for (int i = 0; i < 32; ++i)
      acc[i] += *(const f32x4*)(mrg + i * 1024 + lane * 16);

    // ---- epilogue: Lorentz normalization (softmax denom cancels)
#pragma unroll
    for (int r = 0; r < 4; ++r) {
      float ss = 0.f;
#pragma unroll
      for (int dtl = 0; dtl < 32; ++dtl) ss += acc[dtl][r] * acc[dtl][r];
      ss += __shfl_xor(ss, 1);
      ss += __shfl_xor(ss, 2);
      ss += __shfl_xor(ss, 4);
      ss += __shfl_xor(ss, 8);
      float a0 = __shfl(acc[0][r], lane & 48);       // lane c==0 holds O[q][0]
      float d2 = fabsf(2.f * a0 * a0 - ss);
      float inv = rsqrtf(fmaxf(d2, 1e-8f));
      float* orow = out + ((size_t)(b * NSEQ + q0 + 4 * g + r)) * DIM + c;
#pragma unroll
      for (int dtl = 0; dtl < 32; ++dtl) orow[dtl * 16] = acc[dtl][r] * inv;
    }
  }
}

extern "C" void kernel_launch(void* const* d_in, const int* in_sizes, int n_in,
                              void* d_out, int out_size, void* d_ws, size_t ws_size,
                              hipStream_t stream) {
  (void)in_sizes; (void)n_in; (void)out_size;
  const float* qs = (const float*)d_in[0];
  const float* ks = (const float*)d_in[1];
  const float* vs = (const float*)d_in[2];
  const float* scale = (const float*)d_in[3];
  // d_in[4] (bias) is uniform across softmax axis -> invariant -> unused
  float* out = (float*)d_out;

  size_t need = (size_t)2 * 8 * 64 * TILEB;   // 33.5 MB
  if (ws_size < need) return;
  char* kp  = (char*)d_ws;
  char* vtp = (char*)d_ws + (size_t)8 * 64 * TILEB;

  hipFuncSetAttribute((const void*)attn_main,
                      hipFuncAttributeMaxDynamicSharedMemorySize, SMEMB);

  prep_k<<<512, 256, 0, stream>>>(ks, kp);
  prep_v<<<512, 256, 0, stream>>>(vs, vtp);
  attn_main<<<256, 512, SMEMB, stream>>>(qs, kp, vtp, scale, out);
}

// Round 8
// 154.612 us; speedup vs baseline: 1.3143x; 1.1612x over previous
//
#include <hip/hip_runtime.h>

#define NSEQ 2048
#define DIM  512
#define KVBLK 32
#define NKT  64                    // 2048 / 32
#define TILEB 32768                // 32*512*2 bytes (bf16 tile)
#define SMEMB4 (4 * TILEB + 4096)  // 4-wave variant: K0,K1,V0,V1 + 4x1KB P
#define SMEMB8 (4 * TILEB + 8192)  // 8-wave variant: + 8x1KB P

typedef __bf16 bf16x8 __attribute__((ext_vector_type(8)));
typedef float  f32x4  __attribute__((ext_vector_type(4)));

__device__ __forceinline__ void gld16(const void* g, void* l) {
  __builtin_amdgcn_global_load_lds(
      (const __attribute__((address_space(1))) unsigned int*)g,
      (__attribute__((address_space(3))) unsigned int*)l, 16, 0, 0);
}

// ---------- pre-pass: K -> bf16, per-tile [32 kv][512 d], byte ^= ((row&7)<<4)
__global__ __launch_bounds__(256) void prep_k(const float* __restrict__ ks,
                                              char* __restrict__ kp) {
  int b = blockIdx.x >> 6, kt = blockIdx.x & 63;
  int t = threadIdx.x;
  const float* src = ks + ((size_t)(b * NSEQ + kt * KVBLK)) * DIM;
  char* dst = kp + ((size_t)(b * 64 + kt)) * TILEB;
#pragma unroll
  for (int i = 0; i < 8; ++i) {
    int c = t + i * 256;
    int row = c >> 6;
    int d0 = (c & 63) * 8;
    const float4* s4 = (const float4*)(src + row * DIM + d0);
    float4 x = s4[0], y = s4[1];
    bf16x8 h;
    h[0] = (__bf16)x.x; h[1] = (__bf16)x.y; h[2] = (__bf16)x.z; h[3] = (__bf16)x.w;
    h[4] = (__bf16)y.x; h[5] = (__bf16)y.y; h[6] = (__bf16)y.z; h[7] = (__bf16)y.w;
    *(bf16x8*)(dst + row * 1024 + ((d0 * 2) ^ ((row & 7) << 4))) = h;
  }
}

// ---------- pre-pass: V -> bf16 transposed per tile (verified layout):
// byte(d,kv) = (d>>1)*128 + ((((d&1)*64) + kv*2) ^ (((d>>1)&7)<<4))
__global__ __launch_bounds__(256) void prep_v(const float* __restrict__ vs,
                                              char* __restrict__ vtp) {
  __shared__ __align__(16) char lds[TILEB];
  int b = blockIdx.x >> 6, kt = blockIdx.x & 63;
  int t = threadIdx.x;
  const float* src = vs + ((size_t)(b * NSEQ + kt * KVBLK)) * DIM;
#pragma unroll
  for (int i = 0; i < 8; ++i) {
    int c = t + i * 256;
    int kv = c >> 6;
    int d0 = (c & 63) * 8;
    const float4* s4 = (const float4*)(src + kv * DIM + d0);
    float4 x = s4[0], y = s4[1];
    float vals[8] = {x.x, x.y, x.z, x.w, y.x, y.y, y.z, y.w};
#pragma unroll
    for (int j = 0; j < 8; ++j) {
      int d = d0 + j;
      int byte = (d >> 1) * 128 + (((((d & 1) * 64) + kv * 2)) ^ (((d >> 1) & 7) << 4));
      *(__bf16*)(lds + byte) = (__bf16)vals[j];
    }
  }
  __syncthreads();
  char* dst = vtp + ((size_t)(b * 64 + kt)) * TILEB;
#pragma unroll
  for (int i = 0; i < 8; ++i) {
    int c16 = t + i * 256;
    *(bf16x8*)(dst + c16 * 16) = *(const bf16x8*)(lds + c16 * 16);
  }
}

// ---------- shared body: NW independent waves x 16q, 2-stage pipeline
// QK(t+1) || PV(t), lane-local softmax, per-wave P LDS roundtrip (R5-verified)
template<int NW>
__device__ __forceinline__ void attn_body(
    const float* __restrict__ qs, const char* __restrict__ kp,
    const char* __restrict__ vtp, const float* __restrict__ scale,
    float* __restrict__ out, char* smem, int bid, int tid) {
  constexpr int NT = NW * 64;                 // threads per block
  constexpr int SI = TILEB / (NT * 16);       // stage issues per 32KB tile
  int b  = bid & 7;                           // batch -> XCD (L2 locality)
  int qt = bid >> 3;
  int w = tid >> 6, lane = tid & 63;
  int c = lane & 15, g = lane >> 4;
  int q0 = qt * (NW * 16) + w * 16;

  char* kbuf = smem;                // + (i&1)*TILEB
  char* vbuf = smem + 2 * TILEB;    // + (i&1)*TILEB
  char* plds = smem + 4 * TILEB + w * 1024;

  float cc = 1.4426950408889634f / scale[0];   // log2(e)/scale folded into Q

  // Q fragments (B-operand for swapped QK; lane holds Q[q=c][k*32+g*8..+7])
  bf16x8 qf[16];
#pragma unroll
  for (int k = 0; k < 16; ++k) {
    int d = k * 32 + g * 8;
    const float4* p = (const float4*)(qs + ((size_t)(b * NSEQ + q0 + c)) * DIM + d);
    float4 x = p[0], y = p[1];
    float vals[8] = {x.x, x.y, x.z, x.w, y.x, y.y, y.z, y.w};
    bf16x8 h;
#pragma unroll
    for (int j = 0; j < 8; ++j) {
      float mlt = (d + j == 0) ? cc : -cc;     // Minkowski sign fold
      h[j] = (__bf16)(vals[j] * mlt);
    }
    qf[k] = h;
  }

  f32x4 acc[32];
#pragma unroll
  for (int i = 0; i < 32; ++i) acc[i] = (f32x4){0.f, 0.f, 0.f, 0.f};
  float mrow = -1e30f;               // running max for q=c (lane-local)

  const char* kpb = kp  + (size_t)b * 64 * TILEB;
  const char* vpb = vtp + (size_t)b * 64 * TILEB;

  const int csw = (c & 7) << 4;                // K swizzle term
  const int vt_lane = (c >> 1) * 128 +
      (((((c & 1) * 64) + g * 16)) ^ (((c >> 1) & 7) << 4));  // V/P A-frag read
  const int qb = (c >> 1) * 128;               // P write-side (q=c per lane)
  const int qh = (c & 1) * 64;
  const int qx = ((c >> 1) & 7) << 4;

  // prologue: stage K(0), V(0), K(1)
#pragma unroll
  for (int i = 0; i < SI; ++i) {
    int o = tid * 16 + i * (NT * 16);
    gld16(kpb + o, kbuf + o);
    gld16(vpb + o, vbuf + o);
    gld16(kpb + TILEB + o, kbuf + TILEB + o);
  }
  __syncthreads();

  f32x4 sl, sh;
  bf16x8 pf;

  // ---- QK(0) + softmax(0) + P(0)
  {
    f32x4 sa0 = {0.f,0.f,0.f,0.f}, sb0 = {0.f,0.f,0.f,0.f};
    f32x4 sa1 = {0.f,0.f,0.f,0.f}, sb1 = {0.f,0.f,0.f,0.f};
    const char* krl = kbuf + c * 1024;
    const char* krh = krl + 16 * 1024;
#pragma unroll
    for (int k = 0; k < 16; ++k) {
      int bir = (k * 64 + g * 16) ^ csw;
      bf16x8 kfl = *(const bf16x8*)(krl + bir);
      bf16x8 kfh = *(const bf16x8*)(krh + bir);
      if (k & 1) {
        sb0 = __builtin_amdgcn_mfma_f32_16x16x32_bf16(kfl, qf[k], sb0, 0, 0, 0);
        sb1 = __builtin_amdgcn_mfma_f32_16x16x32_bf16(kfh, qf[k], sb1, 0, 0, 0);
      } else {
        sa0 = __builtin_amdgcn_mfma_f32_16x16x32_bf16(kfl, qf[k], sa0, 0, 0, 0);
        sa1 = __builtin_amdgcn_mfma_f32_16x16x32_bf16(kfh, qf[k], sa1, 0, 0, 0);
      }
    }
    sl = sa0 + sb0; sh = sa1 + sb1;
    float mm = fmaxf(fmaxf(fmaxf(sl[0], sl[1]), fmaxf(sl[2], sl[3])),
                     fmaxf(fmaxf(sh[0], sh[1]), fmaxf(sh[2], sh[3])));
    mm = fmaxf(mm, __shfl_xor(mm, 16));
    mm = fmaxf(mm, __shfl_xor(mm, 32));
    mrow = mm;                                  // first tile: just set
#pragma unroll
    for (int r = 0; r < 4; ++r) {
      float pvl = exp2f(sl[r] - mrow);
      float pvh = exp2f(sh[r] - mrow);
      int kvl = 4 * g + r;
      *(__bf16*)(plds + qb + ((qh + kvl * 2) ^ qx))        = (__bf16)pvl;
      *(__bf16*)(plds + qb + ((qh + (16 + kvl) * 2) ^ qx)) = (__bf16)pvh;
    }
    pf = *(const bf16x8*)(plds + vt_lane);
  }
  __syncthreads();   // protect kbuf0 (all waves done with QK(0)) before K(2) stage

  // ---- pipelined main loop: iter t does QK(t+1) || PV(t)
  for (int t = 0; t < NKT - 1; ++t) {
    if (t + 2 < NKT) {
      const char* ksrc = kpb + (size_t)(t + 2) * TILEB;
      char* kdst = kbuf + (t & 1) * TILEB;
#pragma unroll
      for (int i = 0; i < SI; ++i) {
        int o = tid * 16 + i * (NT * 16);
        gld16(ksrc + o, kdst + o);
      }
    }
    {
      const char* vsrc = vpb + (size_t)(t + 1) * TILEB;
      char* vdst = vbuf + ((t + 1) & 1) * TILEB;
#pragma unroll
      for (int i = 0; i < SI; ++i) {
        int o = tid * 16 + i * (NT * 16);
        gld16(vsrc + o, vdst + o);
      }
    }

    // ---- merged region: QK(t+1) reads kbuf[(t+1)&1]; PV(t) reads vbuf[t&1]
    f32x4 sa0 = {0.f,0.f,0.f,0.f}, sb0 = {0.f,0.f,0.f,0.f};
    f32x4 sa1 = {0.f,0.f,0.f,0.f}, sb1 = {0.f,0.f,0.f,0.f};
    const char* krl = kbuf + ((t + 1) & 1) * TILEB + c * 1024;
    const char* krh = krl + 16 * 1024;
    const char* vr  = vbuf + (t & 1) * TILEB + vt_lane;
#pragma unroll
    for (int k = 0; k < 16; ++k) {
      int bir = (k * 64 + g * 16) ^ csw;
      bf16x8 kfl = *(const bf16x8*)(krl + bir);
      bf16x8 kfh = *(const bf16x8*)(krh + bir);
      bf16x8 vf0 = *(const bf16x8*)(vr + (2 * k) * 1024);
      bf16x8 vf1 = *(const bf16x8*)(vr + (2 * k + 1) * 1024);
      if (k & 1) {
        sb0 = __builtin_amdgcn_mfma_f32_16x16x32_bf16(kfl, qf[k], sb0, 0, 0, 0);
        sb1 = __builtin_amdgcn_mfma_f32_16x16x32_bf16(kfh, qf[k], sb1, 0, 0, 0);
      } else {
        sa0 = __builtin_amdgcn_mfma_f32_16x16x32_bf16(kfl, qf[k], sa0, 0, 0, 0);
        sa1 = __builtin_amdgcn_mfma_f32_16x16x32_bf16(kfh, qf[k], sa1, 0, 0, 0);
      }
      acc[2 * k]     = __builtin_amdgcn_mfma_f32_16x16x32_bf16(pf, vf0, acc[2 * k], 0, 0, 0);
      acc[2 * k + 1] = __builtin_amdgcn_mfma_f32_16x16x32_bf16(pf, vf1, acc[2 * k + 1], 0, 0, 0);
    }
    sl = sa0 + sb0; sh = sa1 + sb1;

    // ---- softmax(t+1) (lane-local row q=c; reduce over g only)
    float mm = fmaxf(fmaxf(fmaxf(sl[0], sl[1]), fmaxf(sl[2], sl[3])),
                     fmaxf(fmaxf(sh[0], sh[1]), fmaxf(sh[2], sh[3])));
    mm = fmaxf(mm, __shfl_xor(mm, 16));
    mm = fmaxf(mm, __shfl_xor(mm, 32));
    if (__any(mm > mrow + 11.0f)) {          // defer-max (2^11 headroom)
      float mn = fmaxf(mrow, mm);
      float f = exp2f(mrow - mn);
      mrow = mn;
      float f0 = __shfl(f, 4 * g + 0), f1 = __shfl(f, 4 * g + 1);
      float f2 = __shfl(f, 4 * g + 2), f3 = __shfl(f, 4 * g + 3);
#pragma unroll
      for (int i = 0; i < 32; ++i) {
        acc[i][0] *= f0; acc[i][1] *= f1; acc[i][2] *= f2; acc[i][3] *= f3;
      }
    }

    // ---- P(t+1) write + A-frag read (per-wave LDS, no barrier needed)
#pragma unroll
    for (int r = 0; r < 4; ++r) {
      float pvl = exp2f(sl[r] - mrow);
      float pvh = exp2f(sh[r] - mrow);
      int kvl = 4 * g + r;
      *(__bf16*)(plds + qb + ((qh + kvl * 2) ^ qx))        = (__bf16)pvl;
      *(__bf16*)(plds + qb + ((qh + (16 + kvl) * 2) ^ qx)) = (__bf16)pvh;
    }
    pf = *(const bf16x8*)(plds + vt_lane);

    __syncthreads();   // drain stages; all waves done reading this iter's buffers
  }

  // ---- tail: PV(NKT-1)
  {
    const char* vr = vbuf + ((NKT - 1) & 1) * TILEB + vt_lane;
#pragma unroll
    for (int dtl = 0; dtl < 32; ++dtl) {
      bf16x8 vf = *(const bf16x8*)(vr + dtl * 1024);
      acc[dtl] = __builtin_amdgcn_mfma_f32_16x16x32_bf16(pf, vf, acc[dtl], 0, 0, 0);
    }
  }

  // ---- epilogue: Lorentz normalization (softmax denom cancels; EPS preserved)
#pragma unroll
  for (int r = 0; r < 4; ++r) {
    float ss = 0.f;
#pragma unroll
    for (int dtl = 0; dtl < 32; ++dtl) ss += acc[dtl][r] * acc[dtl][r];
    ss += __shfl_xor(ss, 1);
    ss += __shfl_xor(ss, 2);
    ss += __shfl_xor(ss, 4);
    ss += __shfl_xor(ss, 8);
    float a0 = __shfl(acc[0][r], lane & 48);   // lane c==0 holds O[q][0]
    float d2 = fabsf(2.f * a0 * a0 - ss);
    float inv = rsqrtf(fmaxf(d2, 1e-8f));
    float* orow = out + ((size_t)(b * NSEQ + q0 + 4 * g + r)) * DIM + c;
#pragma unroll
    for (int dtl = 0; dtl < 32; ++dtl) orow[dtl * 16] = acc[dtl][r] * inv;
  }
}

// 4-wave variant (R5-proven codegen, fallback)
__global__ __launch_bounds__(256) void attn_main4(
    const float* __restrict__ qs, const char* __restrict__ kp,
    const char* __restrict__ vtp, const float* __restrict__ scale,
    float* __restrict__ out) {
  extern __shared__ __align__(16) char smem[];
  attn_body<4>(qs, kp, vtp, scale, out, smem, blockIdx.x, threadIdx.x);
}

// 8-wave variant: waves_per_eu(2,2) raises VGPR budget to 256/wave
__global__
__attribute__((amdgpu_flat_work_group_size(512, 512)))
__attribute__((amdgpu_waves_per_eu(2, 2)))
void attn_main8(
    const float* __restrict__ qs, const char* __restrict__ kp,
    const char* __restrict__ vtp, const float* __restrict__ scale,
    float* __restrict__ out) {
  extern __shared__ __align__(16) char smem[];
  attn_body<8>(qs, kp, vtp, scale, out, smem, blockIdx.x, threadIdx.x);
}

extern "C" void kernel_launch(void* const* d_in, const int* in_sizes, int n_in,
                              void* d_out, int out_size, void* d_ws, size_t ws_size,
                              hipStream_t stream) {
  (void)in_sizes; (void)n_in; (void)out_size;
  const float* qs = (const float*)d_in[0];
  const float* ks = (const float*)d_in[1];
  const float* vs = (const float*)d_in[2];
  const float* scale = (const float*)d_in[3];
  // d_in[4] (bias) is uniform across softmax axis -> invariant -> unused
  float* out = (float*)d_out;

  size_t need = (size_t)2 * 8 * 64 * TILEB;   // 33.5 MB
  if (ws_size < need) return;
  char* kp  = (char*)d_ws;
  char* vtp = (char*)d_ws + (size_t)8 * 64 * TILEB;

  prep_k<<<512, 256, 0, stream>>>(ks, kp);
  prep_v<<<512, 256, 0, stream>>>(vs, vtp);

  // pick 8-wave variant only if it compiled without spill and with a real
  // register budget (deterministic host-side query; graph-capture safe)
  hipFuncAttributes a8;
  bool use8 = false;
  if (hipFuncGetAttributes(&a8, (const void*)attn_main8) == hipSuccess)
    use8 = (a8.localSizeBytes == 0 && a8.numRegs >= 150);

  if (use8) {
    hipFuncSetAttribute((const void*)attn_main8,
                        hipFuncAttributeMaxDynamicSharedMemorySize, SMEMB8);
    attn_main8<<<128, 512, SMEMB8, stream>>>(qs, kp, vtp, scale, out);
  } else {
    hipFuncSetAttribute((const void*)attn_main4,
                        hipFuncAttributeMaxDynamicSharedMemorySize, SMEMB4);
    attn_main4<<<256, 256, SMEMB4, stream>>>(qs, kp, vtp, scale, out);
  }
}